// Round 1
// baseline (1998.489 us; speedup 1.0000x reference)
//
#include <hip/hip_runtime.h>
#include <hip/hip_bf16.h>
#include <math.h>

#define D_MODEL 768
#define T_SEQ   1024
#define BATCH   4
#define NCH     7
#define ROWS    (BATCH * T_SEQ)   // 4096

typedef unsigned short u16;
typedef __attribute__((ext_vector_type(8))) short bh8;   // 8 x bf16 (4 VGPRs)
typedef __attribute__((ext_vector_type(4))) float f32x4;

__device__ __forceinline__ u16 f2bf(float f) {
    union { float f; unsigned u; } v; v.f = f;
    return (u16)((v.u + 0x7fffu + ((v.u >> 16) & 1u)) >> 16);  // RNE
}

__device__ __forceinline__ float wred_sum(float v) {
    #pragma unroll
    for (int o = 32; o; o >>= 1) v += __shfl_down(v, o, 64);
    return v;
}
__device__ __forceinline__ float wred_max(float v) {
    #pragma unroll
    for (int o = 32; o; o >>= 1) v = fmaxf(v, __shfl_down(v, o, 64));
    return v;
}

#define GLD16(g, l) __builtin_amdgcn_global_load_lds( \
    (const __attribute__((address_space(1))) void*)(g), \
    (__attribute__((address_space(3))) void*)(l), 16, 0, 0)

// ---------------------------------------------------------------------------
// Generic NT GEMM: C[M,N] = alpha * A[M,K] * B[N,K]^T   (A,B bf16 row-major)
// mode 0: C fp32 store; mode 1: C bf16 store; mode 2: C fp32 accumulate
// causal_skip: skip tiles with col-block > row-block (scores QK^T)
// causal_k:    limit K to (bm+1)*128 (PV with zeroed upper-tri P)
// All of M,N divisible by 128; K divisible by 32.
// ---------------------------------------------------------------------------
__global__ __launch_bounds__(256)
void gemm_nt_kernel(const u16* __restrict__ A, const u16* __restrict__ B,
                    void* __restrict__ Cv,
                    int M, int N, int K, int lda, int ldb, int ldc,
                    long long sA, long long sB, long long sC,
                    float alpha, int mode, int causal_skip, int causal_k)
{
    int bn = blockIdx.x, bm = blockIdx.y, bz = blockIdx.z;
    if (causal_skip && bn > bm) return;

    const u16* Ab = A + (long long)bz * sA + (long long)(bm * 128) * lda;
    const u16* Bb = B + (long long)bz * sB + (long long)(bn * 128) * ldb;

    __shared__ u16 sm[2 * 128 * 32];       // 16 KB, unpadded (global_load_lds)
    u16* Al = sm;
    u16* Bl = sm + 128 * 32;

    int tid  = threadIdx.x;
    int lane = tid & 63;
    int wave = tid >> 6;
    int wm = wave >> 1;                    // 2x2 wave grid over 128x128 tile
    int wn = wave & 1;

    int Kl = causal_k ? min(K, (bm + 1) * 128) : K;

    f32x4 acc[4][4];
    #pragma unroll
    for (int i = 0; i < 4; i++)
        #pragma unroll
        for (int j = 0; j < 4; j++)
            acc[i][j] = (f32x4){0.f, 0.f, 0.f, 0.f};

    int srow = lane >> 2;                  // staging: row within 16-row chunk
    int skq  = (lane & 3) * 8;             // 16B quarter of 32-elem k-slice
    int fm   = lane & 15;                  // fragment row/col
    int fk   = (lane >> 4) * 8;            // fragment k-offset

    for (int k0 = 0; k0 < Kl; k0 += 32) {
        __syncthreads();                   // LDS reuse from previous iter
        #pragma unroll
        for (int r = 0; r < 2; r++) {
            int row = r * 64 + wave * 16 + srow;
            GLD16(Ab + (long long)row * lda + k0 + skq, Al + row * 32 + skq);
            GLD16(Bb + (long long)row * ldb + k0 + skq, Bl + row * 32 + skq);
        }
        __syncthreads();                   // compiler drains vmcnt before barrier

        bh8 af[4], bf[4];
        #pragma unroll
        for (int i = 0; i < 4; i++)
            af[i] = *(const bh8*)(Al + (wm * 64 + i * 16 + fm) * 32 + fk);
        #pragma unroll
        for (int j = 0; j < 4; j++)
            bf[j] = *(const bh8*)(Bl + (wn * 64 + j * 16 + fm) * 32 + fk);
        #pragma unroll
        for (int i = 0; i < 4; i++)
            #pragma unroll
            for (int j = 0; j < 4; j++)
                acc[i][j] = __builtin_amdgcn_mfma_f32_16x16x32_bf16(af[i], bf[j], acc[i][j], 0, 0, 0);
    }

    // C/D layout: col = lane&15, row = (lane>>4)*4 + reg
    int rbase = bm * 128 + wm * 64 + (lane >> 4) * 4;
    int cbase = bn * 128 + wn * 64 + (lane & 15);
    if (mode == 1) {
        u16* C = (u16*)Cv + (long long)bz * sC;
        #pragma unroll
        for (int i = 0; i < 4; i++)
            #pragma unroll
            for (int j = 0; j < 4; j++)
                #pragma unroll
                for (int r = 0; r < 4; r++)
                    C[(long long)(rbase + i * 16 + r) * ldc + cbase + j * 16] = f2bf(acc[i][j][r] * alpha);
    } else if (mode == 0) {
        float* C = (float*)Cv + (long long)bz * sC;
        #pragma unroll
        for (int i = 0; i < 4; i++)
            #pragma unroll
            for (int j = 0; j < 4; j++)
                #pragma unroll
                for (int r = 0; r < 4; r++)
                    C[(long long)(rbase + i * 16 + r) * ldc + cbase + j * 16] = acc[i][j][r] * alpha;
    } else {
        float* C = (float*)Cv + (long long)bz * sC;
        #pragma unroll
        for (int i = 0; i < 4; i++)
            #pragma unroll
            for (int j = 0; j < 4; j++)
                #pragma unroll
                for (int r = 0; r < 4; r++) {
                    long long idx = (long long)(rbase + i * 16 + r) * ldc + cbase + j * 16;
                    C[idx] += acc[i][j][r] * alpha;
                }
    }
}

// ---------------------------------------------------------------------------
// LN pre: h = LN(x)*g + b   (one block per row, 256 thr, 3 elems/thr)
// ---------------------------------------------------------------------------
__global__ __launch_bounds__(256)
void ln_pre_kernel(const float* __restrict__ x, const float* __restrict__ g,
                   const float* __restrict__ b, float* __restrict__ h)
{
    int row = blockIdx.x;
    long long base = (long long)row * D_MODEL;
    int tid = threadIdx.x, lane = tid & 63, wave = tid >> 6;
    __shared__ float red[4];
    float v[3]; float s = 0.f;
    #pragma unroll
    for (int k = 0; k < 3; k++) { v[k] = x[base + tid + k * 256]; s += v[k]; }
    s = wred_sum(s);
    if (lane == 0) red[wave] = s;
    __syncthreads();
    float mean = (red[0] + red[1] + red[2] + red[3]) * (1.f / D_MODEL);
    __syncthreads();
    float sq = 0.f;
    #pragma unroll
    for (int k = 0; k < 3; k++) { float d = v[k] - mean; sq += d * d; }
    sq = wred_sum(sq);
    if (lane == 0) red[wave] = sq;
    __syncthreads();
    float var = (red[0] + red[1] + red[2] + red[3]) * (1.f / D_MODEL);
    float rstd = rsqrtf(var + 1e-5f);
    #pragma unroll
    for (int k = 0; k < 3; k++) {
        int c = tid + k * 256;
        h[base + c] = (v[k] - mean) * rstd * g[c] + b[c];
    }
}

// ---------------------------------------------------------------------------
// prep: hh = h (+ seq) -> bf16 row-major (B,T,D) AND transposed (B,D,T)
// grid (D/32, T/32, B), 256 threads
// ---------------------------------------------------------------------------
__global__ __launch_bounds__(256)
void prep_kernel(const float* __restrict__ h, const float* __restrict__ seq,
                 u16* __restrict__ hb, u16* __restrict__ ht)
{
    __shared__ u16 tile[32][33];
    int b = blockIdx.z;
    int d0 = blockIdx.x * 32, t0 = blockIdx.y * 32;
    int tx = threadIdx.x & 31, ty = threadIdx.x >> 5;   // ty 0..7
    long long bb = (long long)b * T_SEQ * D_MODEL;
    #pragma unroll
    for (int i = 0; i < 32; i += 8) {
        long long idx = bb + (long long)(t0 + ty + i) * D_MODEL + d0 + tx;
        float v = h[idx];
        if (seq) v += seq[idx];
        u16 w = f2bf(v);
        hb[idx] = w;
        tile[ty + i][tx] = w;
    }
    __syncthreads();
    #pragma unroll
    for (int i = 0; i < 32; i += 8)
        ht[bb + (long long)(d0 + ty + i) * T_SEQ + t0 + tx] = tile[tx][ty + i];
}

// ---------------------------------------------------------------------------
// causal softmax over fp32 scores -> bf16 P, zero-filled above diagonal
// grid (T, B), 256 threads, row cached in 4 regs
// ---------------------------------------------------------------------------
__global__ __launch_bounds__(256)
void softmax_kernel(const float* __restrict__ S, u16* __restrict__ P)
{
    int t = blockIdx.x, b = blockIdx.y;
    long long rb = ((long long)b * T_SEQ + t) * T_SEQ;
    const float* row = S + rb;
    u16* prow = P + rb;
    int len = t + 1;
    int tid = threadIdx.x, lane = tid & 63, wave = tid >> 6;
    __shared__ float red[4];

    float ev[4];
    float m = -3.0e38f;
    #pragma unroll
    for (int k = 0; k < 4; k++) {
        int s = tid + k * 256;
        ev[k] = (s < len) ? row[s] : -3.0e38f;
        m = fmaxf(m, ev[k]);
    }
    m = wred_max(m);
    if (lane == 0) red[wave] = m;
    __syncthreads();
    m = fmaxf(fmaxf(red[0], red[1]), fmaxf(red[2], red[3]));
    __syncthreads();
    float sum = 0.f;
    #pragma unroll
    for (int k = 0; k < 4; k++) {
        int s = tid + k * 256;
        float e = (s < len) ? __expf(ev[k] - m) : 0.f;
        ev[k] = e; sum += e;
    }
    sum = wred_sum(sum);
    if (lane == 0) red[wave] = sum;
    __syncthreads();
    sum = red[0] + red[1] + red[2] + red[3];
    float inv = 1.f / sum;
    #pragma unroll
    for (int k = 0; k < 4; k++)
        prow[tid + k * 256] = f2bf(ev[k] * inv);
}

// ---------------------------------------------------------------------------
// delta: gate = sigmoid(dot(hh,gw)+gb); d = softplus(sp)*mask*gate*(E-hh)
// seq != null:  seq += d  (hh = h+seq)     dbf != null: dbf = bf16(d) (hh = h)
// one block per row
// ---------------------------------------------------------------------------
__global__ __launch_bounds__(256)
void delta_kernel(const float* __restrict__ E, const float* __restrict__ h,
                  float* __restrict__ seq, u16* __restrict__ dbf,
                  const float* __restrict__ gw, const float* __restrict__ gb,
                  const float* __restrict__ sp, int ci, float mask)
{
    int row = blockIdx.x;
    long long base = (long long)row * D_MODEL;
    int tid = threadIdx.x, lane = tid & 63, wave = tid >> 6;
    __shared__ float red[4];
    float hh[3]; float dot = 0.f;
    #pragma unroll
    for (int k = 0; k < 3; k++) {
        int c = tid + k * 256;
        float v = h[base + c];
        if (seq) v += seq[base + c];
        hh[k] = v;
        dot += v * gw[ci * D_MODEL + c];
    }
    dot = wred_sum(dot);
    if (lane == 0) red[wave] = dot;
    __syncthreads();
    dot = red[0] + red[1] + red[2] + red[3];
    float gate = 1.f / (1.f + expf(-(dot + gb[ci])));
    float coef = log1pf(expf(sp[ci])) * mask * gate;
    #pragma unroll
    for (int k = 0; k < 3; k++) {
        int c = tid + k * 256;
        float d = coef * (E[base + c] - hh[k]);
        if (seq) seq[base + c] += d;
        else     dbf[base + c] = f2bf(d);
    }
}

// ---------------------------------------------------------------------------
// weight transpose+cast: WT[z][d][e] = bf16(W[z][e][d]); grid (24,24,NCH)
// ---------------------------------------------------------------------------
__global__ __launch_bounds__(256)
void transw_kernel(const float* __restrict__ W, u16* __restrict__ WT)
{
    __shared__ u16 tile[32][33];
    int z = blockIdx.z;
    int c0 = blockIdx.x * 32, r0 = blockIdx.y * 32;
    int tx = threadIdx.x & 31, ty = threadIdx.x >> 5;
    long long bb = (long long)z * D_MODEL * D_MODEL;
    #pragma unroll
    for (int i = 0; i < 32; i += 8)
        tile[ty + i][tx] = f2bf(W[bb + (long long)(r0 + ty + i) * D_MODEL + c0 + tx]);
    __syncthreads();
    #pragma unroll
    for (int i = 0; i < 32; i += 8)
        WT[bb + (long long)(c0 + ty + i) * D_MODEL + r0 + tx] = tile[tx][ty + i];
}

__global__ __launch_bounds__(256)
void cast_kernel(const float* __restrict__ in, u16* __restrict__ outp, int n)
{
    int i = blockIdx.x * 256 + threadIdx.x;
    if (i < n) outp[i] = f2bf(in[i]);
}

// ---------------------------------------------------------------------------
// final: e = (1-mg)*seq + mg*par; out = x + rg * LN(e)*g + b form
// ---------------------------------------------------------------------------
__global__ __launch_bounds__(256)
void final_kernel(const float* __restrict__ x, const float* __restrict__ seq,
                  const float* __restrict__ par,
                  const float* __restrict__ mode_logit, const float* __restrict__ residual_gate,
                  const float* __restrict__ g, const float* __restrict__ b,
                  float* __restrict__ out)
{
    int row = blockIdx.x;
    long long base = (long long)row * D_MODEL;
    int tid = threadIdx.x, lane = tid & 63, wave = tid >> 6;
    __shared__ float red[4];
    float mg = 1.f / (1.f + expf(-mode_logit[0]));
    float rg = residual_gate[0];
    float e[3]; float s = 0.f;
    #pragma unroll
    for (int k = 0; k < 3; k++) {
        int c = tid + k * 256;
        float v = (1.f - mg) * seq[base + c] + mg * par[base + c];
        e[k] = v; s += v;
    }
    s = wred_sum(s);
    if (lane == 0) red[wave] = s;
    __syncthreads();
    float mean = (red[0] + red[1] + red[2] + red[3]) * (1.f / D_MODEL);
    __syncthreads();
    float sq = 0.f;
    #pragma unroll
    for (int k = 0; k < 3; k++) { float d = e[k] - mean; sq += d * d; }
    sq = wred_sum(sq);
    if (lane == 0) red[wave] = sq;
    __syncthreads();
    float var = (red[0] + red[1] + red[2] + red[3]) * (1.f / D_MODEL);
    float rstd = rsqrtf(var + 1e-5f);
    #pragma unroll
    for (int k = 0; k < 3; k++) {
        int c = tid + k * 256;
        out[base + c] = x[base + c] + rg * ((e[k] - mean) * rstd * g[c] + b[c]);
    }
}

// ---------------------------------------------------------------------------
static inline void launch_gemm(hipStream_t st, const u16* A, const u16* B, void* C,
                               int M, int N, int K, int lda, int ldb, int ldc,
                               long long sA, long long sB, long long sC, int batch,
                               float alpha, int mode, int cskip, int ck)
{
    dim3 grid(N / 128, M / 128, batch);
    gemm_nt_kernel<<<grid, 256, 0, st>>>(A, B, C, M, N, K, lda, ldb, ldc,
                                         sA, sB, sC, alpha, mode, cskip, ck);
}

extern "C" void kernel_launch(void* const* d_in, const int* in_sizes, int n_in,
                              void* d_out, int out_size, void* d_ws, size_t ws_size,
                              hipStream_t stream)
{
    (void)in_sizes; (void)n_in; (void)out_size; (void)ws_size;
    const float* x             = (const float*)d_in[0];
    const float* Wq            = (const float*)d_in[1];
    const float* Wk            = (const float*)d_in[2];
    const float* gate_w        = (const float*)d_in[3];
    const float* gate_b        = (const float*)d_in[4];
    const float* scale_p       = (const float*)d_in[5];
    const float* merge_W       = (const float*)d_in[6];
    const float* mode_logit    = (const float*)d_in[7];
    const float* residual_gate = (const float*)d_in[8];
    const float* ln_pre_g      = (const float*)d_in[9];
    const float* ln_pre_b      = (const float*)d_in[10];
    const float* ln_post_g     = (const float*)d_in[11];
    const float* ln_post_b     = (const float*)d_in[12];
    float* out = (float*)d_out;

    size_t off = 0;
    char* wsb = (char*)d_ws;
    auto alloc = [&](size_t bytes) -> void* {
        void* p = wsb + off;
        off += (bytes + 255) & ~(size_t)255;
        return p;
    };
    const size_t RD = (size_t)ROWS * D_MODEL;
    const size_t TT = (size_t)BATCH * T_SEQ * T_SEQ;
    float* h   = (float*)alloc(RD * 4);
    float* seq = (float*)alloc(RD * 4);
    float* par = (float*)alloc(RD * 4);
    float* E   = (float*)alloc(RD * 4);
    float* S   = (float*)alloc(TT * 4);
    u16* hb    = (u16*)alloc(RD * 2);
    u16* ht    = (u16*)alloc(RD * 2);
    u16* qb    = (u16*)alloc(RD * 2);
    u16* kb    = (u16*)alloc(RD * 2);
    u16* Pb    = (u16*)alloc(TT * 2);
    u16* db    = (u16*)alloc(RD * 2);
    u16* WqT   = (u16*)alloc((size_t)NCH * D_MODEL * D_MODEL * 2);
    u16* WkT   = (u16*)alloc((size_t)NCH * D_MODEL * D_MODEL * 2);
    u16* mgb   = (u16*)alloc((size_t)D_MODEL * NCH * D_MODEL * 2);

    // curriculum masks (static: STEP=4000, WARMUP=2000, N=7)
    float masks[NCH];
    {
        double slope = 8.0 * NCH / 2000.0;
        for (int i = 0; i < NCH; i++)
            masks[i] = (float)(1.0 / (1.0 + exp(-slope * (4000.0 - 2000.0 * (i + 0.5) / NCH))));
    }
    const float sc = 1.0f / sqrtf((float)D_MODEL);
    const long long TD = (long long)T_SEQ * D_MODEL;       // 786432
    const long long TTs = (long long)T_SEQ * T_SEQ;        // 1048576
    const int DD = D_MODEL * D_MODEL;
    const int nMerge = D_MODEL * NCH * D_MODEL;

    hipMemsetAsync(seq, 0, RD * 4, stream);
    hipMemsetAsync(par, 0, RD * 4, stream);

    ln_pre_kernel<<<ROWS, 256, 0, stream>>>(x, ln_pre_g, ln_pre_b, h);
    transw_kernel<<<dim3(24, 24, NCH), 256, 0, stream>>>(Wq, WqT);
    transw_kernel<<<dim3(24, 24, NCH), 256, 0, stream>>>(Wk, WkT);
    cast_kernel<<<(nMerge + 255) / 256, 256, 0, stream>>>(merge_W, mgb, nMerge);

    // ---------------- par branch (hh = h, fixed) ----------------
    prep_kernel<<<dim3(24, 32, BATCH), 256, 0, stream>>>(h, nullptr, hb, ht);
    for (int i = 0; i < NCH; i++) {
        launch_gemm(stream, hb, WqT + (size_t)i * DD, qb, ROWS, D_MODEL, D_MODEL,
                    D_MODEL, D_MODEL, D_MODEL, 0, 0, 0, 1, 1.f, 1, 0, 0);
        launch_gemm(stream, hb, WkT + (size_t)i * DD, kb, ROWS, D_MODEL, D_MODEL,
                    D_MODEL, D_MODEL, D_MODEL, 0, 0, 0, 1, 1.f, 1, 0, 0);
        launch_gemm(stream, qb, kb, S, T_SEQ, T_SEQ, D_MODEL,
                    D_MODEL, D_MODEL, T_SEQ, TD, TD, TTs, BATCH, sc, 0, 1, 0);
        softmax_kernel<<<dim3(T_SEQ, BATCH), 256, 0, stream>>>(S, Pb);
        launch_gemm(stream, Pb, ht, E, T_SEQ, D_MODEL, T_SEQ,
                    T_SEQ, T_SEQ, D_MODEL, TTs, TD, TD, BATCH, 1.f, 0, 0, 1);
        delta_kernel<<<ROWS, 256, 0, stream>>>(E, h, nullptr, db,
                                               gate_w, gate_b, scale_p, i, masks[i]);
        launch_gemm(stream, db, mgb + (size_t)i * D_MODEL, par, ROWS, D_MODEL, D_MODEL,
                    D_MODEL, NCH * D_MODEL, D_MODEL, 0, 0, 0, 1, 1.f, 2, 0, 0);
    }

    // ---------------- seq branch (hh = h + seq, sequential) ----------------
    for (int i = 0; i < NCH; i++) {
        prep_kernel<<<dim3(24, 32, BATCH), 256, 0, stream>>>(h, seq, hb, ht);
        launch_gemm(stream, hb, WqT + (size_t)i * DD, qb, ROWS, D_MODEL, D_MODEL,
                    D_MODEL, D_MODEL, D_MODEL, 0, 0, 0, 1, 1.f, 1, 0, 0);
        launch_gemm(stream, hb, WkT + (size_t)i * DD, kb, ROWS, D_MODEL, D_MODEL,
                    D_MODEL, D_MODEL, D_MODEL, 0, 0, 0, 1, 1.f, 1, 0, 0);
        launch_gemm(stream, qb, kb, S, T_SEQ, T_SEQ, D_MODEL,
                    D_MODEL, D_MODEL, T_SEQ, TD, TD, TTs, BATCH, sc, 0, 1, 0);
        softmax_kernel<<<dim3(T_SEQ, BATCH), 256, 0, stream>>>(S, Pb);
        launch_gemm(stream, Pb, ht, E, T_SEQ, D_MODEL, T_SEQ,
                    T_SEQ, T_SEQ, D_MODEL, TTs, TD, TD, BATCH, 1.f, 0, 0, 1);
        delta_kernel<<<ROWS, 256, 0, stream>>>(E, h, seq, nullptr,
                                               gate_w, gate_b, scale_p, i, masks[i]);
    }

    final_kernel<<<ROWS, 256, 0, stream>>>(x, seq, par, mode_logit, residual_gate,
                                           ln_post_g, ln_post_b, out);
}

// Round 2
// 1184.114 us; speedup vs baseline: 1.6878x; 1.6878x over previous
//
#include <hip/hip_runtime.h>
#include <hip/hip_bf16.h>
#include <math.h>

#define D_MODEL 768
#define T_SEQ   1024
#define BATCH   4
#define NCH     7
#define ROWS    4096            // BATCH*T_SEQ

typedef unsigned short u16;
typedef __attribute__((ext_vector_type(8))) short bh8;   // 8 x bf16
typedef __attribute__((ext_vector_type(4))) float f32x4;

__device__ __forceinline__ u16 f2bf(float f) {
    union { float f; unsigned u; } v; v.f = f;
    return (u16)((v.u + 0x7fffu + ((v.u >> 16) & 1u)) >> 16);  // RNE
}
__device__ __forceinline__ float bf2f(u16 b) {
    union { unsigned u; float f; } v; v.u = ((unsigned)b) << 16;
    return v.f;
}
__device__ __forceinline__ float wred_sum(float v) {
    #pragma unroll
    for (int o = 32; o; o >>= 1) v += __shfl_down(v, o, 64);
    return v;
}
__device__ __forceinline__ float wred_max(float v) {
    #pragma unroll
    for (int o = 32; o; o >>= 1) v = fmaxf(v, __shfl_down(v, o, 64));
    return v;
}
__device__ __forceinline__ float chamber_mask(int i) {
    float slope = 8.0f * 7.0f / 2000.0f;
    return 1.0f / (1.0f + __expf(-slope * (4000.0f - 2000.0f * (i + 0.5f) / 7.0f)));
}

#define GLD16(g, l) __builtin_amdgcn_global_load_lds( \
    (const __attribute__((address_space(1))) void*)(g), \
    (__attribute__((address_space(3))) void*)(l), 16, 0, 0)

// ---------------------------------------------------------------------------
// Generic NT GEMM: C[M,N] = alpha * A[M,K] * B[N,K]^T  (bf16 in)
// z decomposition: bz1 = bz % zm, bz2 = bz / zm; operand offset = bz1*s?1+bz2*s?2
// mode: 0 f32 store, 1 bf16 store, 3 f16 store, 4 f32 atomicAdd
// causal_skip: skip bn>bm (QK^T).  causal_k: K limited to (bm+1)*128 (PV).
// kss/klen: split-K — k in [bz1*kss, bz1*kss+klen)
// ---------------------------------------------------------------------------
__global__ __launch_bounds__(256)
void gemm_nt_kernel(const u16* __restrict__ A, const u16* __restrict__ B,
                    void* __restrict__ Cv,
                    int K, int lda, int ldb, int ldc,
                    long long sA1, long long sA2, long long sB1, long long sB2,
                    long long sC1, long long sC2, int zm,
                    float alpha, int mode, int causal_skip, int causal_k,
                    int kss, int klen)
{
    int bn = blockIdx.x, bm = blockIdx.y, bz = blockIdx.z;
    if (causal_skip && bn > bm) return;
    int bz1 = bz % zm, bz2 = bz / zm;

    const u16* Ab = A + bz1 * sA1 + bz2 * sA2 + (long long)(bm * 128) * lda;
    const u16* Bb = B + bz1 * sB1 + bz2 * sB2 + (long long)(bn * 128) * ldb;

    __shared__ u16 sm[2 * 128 * 32];
    u16* Al = sm;
    u16* Bl = sm + 128 * 32;

    int tid  = threadIdx.x;
    int lane = tid & 63;
    int wave = tid >> 6;
    int wm = wave >> 1, wn = wave & 1;

    int k_begin = kss ? bz1 * kss : 0;
    int k_end   = klen ? (k_begin + klen) : K;
    if (causal_k) k_end = min(k_end, (bm + 1) * 128);

    f32x4 acc[4][4];
    #pragma unroll
    for (int i = 0; i < 4; i++)
        #pragma unroll
        for (int j = 0; j < 4; j++)
            acc[i][j] = (f32x4){0.f, 0.f, 0.f, 0.f};

    int srow = lane >> 2;
    int skq  = (lane & 3) * 8;
    int fm   = lane & 15;
    int fk   = (lane >> 4) * 8;

    for (int k0 = k_begin; k0 < k_end; k0 += 32) {
        __syncthreads();
        #pragma unroll
        for (int r = 0; r < 2; r++) {
            int row = r * 64 + wave * 16 + srow;
            GLD16(Ab + (long long)row * lda + k0 + skq, Al + row * 32 + skq);
            GLD16(Bb + (long long)row * ldb + k0 + skq, Bl + row * 32 + skq);
        }
        __syncthreads();

        bh8 af[4], bf[4];
        #pragma unroll
        for (int i = 0; i < 4; i++)
            af[i] = *(const bh8*)(Al + (wm * 64 + i * 16 + fm) * 32 + fk);
        #pragma unroll
        for (int j = 0; j < 4; j++)
            bf[j] = *(const bh8*)(Bl + (wn * 64 + j * 16 + fm) * 32 + fk);
        #pragma unroll
        for (int i = 0; i < 4; i++)
            #pragma unroll
            for (int j = 0; j < 4; j++)
                acc[i][j] = __builtin_amdgcn_mfma_f32_16x16x32_bf16(af[i], bf[j], acc[i][j], 0, 0, 0);
    }

    int rbase = bm * 128 + wm * 64 + (lane >> 4) * 4;
    int cbase = bn * 128 + wn * 64 + (lane & 15);
    long long zoff = bz1 * sC1 + bz2 * sC2;
    if (mode == 1) {
        u16* C = (u16*)Cv + zoff;
        #pragma unroll
        for (int i = 0; i < 4; i++)
            #pragma unroll
            for (int j = 0; j < 4; j++)
                #pragma unroll
                for (int r = 0; r < 4; r++)
                    C[(long long)(rbase + i * 16 + r) * ldc + cbase + j * 16] = f2bf(acc[i][j][r] * alpha);
    } else if (mode == 3) {
        u16* C = (u16*)Cv + zoff;
        #pragma unroll
        for (int i = 0; i < 4; i++)
            #pragma unroll
            for (int j = 0; j < 4; j++)
                #pragma unroll
                for (int r = 0; r < 4; r++) {
                    union { _Float16 h; u16 u; } cv;
                    cv.h = (_Float16)(acc[i][j][r] * alpha);
                    C[(long long)(rbase + i * 16 + r) * ldc + cbase + j * 16] = cv.u;
                }
    } else if (mode == 0) {
        float* C = (float*)Cv + zoff;
        #pragma unroll
        for (int i = 0; i < 4; i++)
            #pragma unroll
            for (int j = 0; j < 4; j++)
                #pragma unroll
                for (int r = 0; r < 4; r++)
                    C[(long long)(rbase + i * 16 + r) * ldc + cbase + j * 16] = acc[i][j][r] * alpha;
    } else {
        float* C = (float*)Cv + zoff;
        #pragma unroll
        for (int i = 0; i < 4; i++)
            #pragma unroll
            for (int j = 0; j < 4; j++)
                #pragma unroll
                for (int r = 0; r < 4; r++)
                    atomicAdd(&C[(long long)(rbase + i * 16 + r) * ldc + cbase + j * 16],
                              acc[i][j][r] * alpha);
    }
}

// ---------------------------------------------------------------------------
// LN pre: h = LN(x)*g+b; also hhf = h (running h+seq) and hb = bf16(h)
// ---------------------------------------------------------------------------
__global__ __launch_bounds__(256)
void ln_pre_kernel(const float* __restrict__ x, const float* __restrict__ g,
                   const float* __restrict__ b, float* __restrict__ h,
                   float* __restrict__ hhf, u16* __restrict__ hb)
{
    int row = blockIdx.x;
    long long base = (long long)row * D_MODEL;
    int tid = threadIdx.x, lane = tid & 63, wave = tid >> 6;
    __shared__ float red[4];
    float v[3]; float s = 0.f;
    #pragma unroll
    for (int k = 0; k < 3; k++) { v[k] = x[base + tid + k * 256]; s += v[k]; }
    s = wred_sum(s);
    if (lane == 0) red[wave] = s;
    __syncthreads();
    float mean = (red[0] + red[1] + red[2] + red[3]) * (1.f / D_MODEL);
    __syncthreads();
    float sq = 0.f;
    #pragma unroll
    for (int k = 0; k < 3; k++) { float d = v[k] - mean; sq += d * d; }
    sq = wred_sum(sq);
    if (lane == 0) red[wave] = sq;
    __syncthreads();
    float var = (red[0] + red[1] + red[2] + red[3]) * (1.f / D_MODEL);
    float rstd = rsqrtf(var + 1e-5f);
    #pragma unroll
    for (int k = 0; k < 3; k++) {
        int c = tid + k * 256;
        float o = (v[k] - mean) * rstd * g[c] + b[c];
        h[base + c] = o; hhf[base + c] = o; hb[base + c] = f2bf(o);
    }
}

// ---------------------------------------------------------------------------
// bf16 transpose: ht[b][d][t] = hb[b][t][d]
// ---------------------------------------------------------------------------
__global__ __launch_bounds__(256)
void transpose_kernel(const u16* __restrict__ hb, u16* __restrict__ ht)
{
    __shared__ u16 tile[32][33];
    int b = blockIdx.z;
    int d0 = blockIdx.x * 32, t0 = blockIdx.y * 32;
    int tx = threadIdx.x & 31, ty = threadIdx.x >> 5;
    long long bb = (long long)b * T_SEQ * D_MODEL;
    #pragma unroll
    for (int i = 0; i < 32; i += 8)
        tile[ty + i][tx] = hb[bb + (long long)(t0 + ty + i) * D_MODEL + d0 + tx];
    __syncthreads();
    #pragma unroll
    for (int i = 0; i < 32; i += 8)
        ht[bb + (long long)(d0 + ty + i) * T_SEQ + t0 + tx] = tile[tx][ty + i];
}

// ---------------------------------------------------------------------------
// causal softmax, f16 scores in -> bf16 P out, IN PLACE (row cached in regs)
// grid (T, Z)
// ---------------------------------------------------------------------------
__global__ __launch_bounds__(256)
void softmax_kernel(u16* __restrict__ SP)
{
    int t = blockIdx.x, z = blockIdx.y;
    long long rb = (long long)z * T_SEQ * T_SEQ + (long long)t * T_SEQ;
    u16* row = SP + rb;
    int len = t + 1;
    int tid = threadIdx.x, lane = tid & 63, wave = tid >> 6;
    __shared__ float red[4];

    float ev[4];
    float m = -3.0e38f;
    #pragma unroll
    for (int k = 0; k < 4; k++) {
        int s = tid + k * 256;
        if (s < len) {
            union { u16 u; _Float16 h; } cv; cv.u = row[s];
            ev[k] = (float)cv.h;
        } else ev[k] = -3.0e38f;
        m = fmaxf(m, ev[k]);
    }
    m = wred_max(m);
    if (lane == 0) red[wave] = m;
    __syncthreads();
    m = fmaxf(fmaxf(red[0], red[1]), fmaxf(red[2], red[3]));
    __syncthreads();
    float sum = 0.f;
    #pragma unroll
    for (int k = 0; k < 4; k++) {
        int s = tid + k * 256;
        float e = (s < len) ? __expf(ev[k] - m) : 0.f;
        ev[k] = e; sum += e;
    }
    sum = wred_sum(sum);
    if (lane == 0) red[wave] = sum;
    __syncthreads();
    sum = red[0] + red[1] + red[2] + red[3];
    float inv = 1.f / sum;
    #pragma unroll
    for (int k = 0; k < 4; k++)
        row[tid + k * 256] = f2bf(ev[k] * inv);
}

// ---------------------------------------------------------------------------
// par deltas, all 7 chambers in one pass per row:
// db[row][i*768+c] = bf16( softplus(sp_i)*mask_i*sigmoid(h.gw_i+gb_i) * (E_i - h) )
// E layout: [(i*4+b)][1024][768] == index (i*4096+row)*768
// ---------------------------------------------------------------------------
__global__ __launch_bounds__(256)
void delta_par_kernel(const u16* __restrict__ E, const float* __restrict__ h,
                      u16* __restrict__ db,
                      const float* __restrict__ gw, const float* __restrict__ gb,
                      const float* __restrict__ sp)
{
    int row = blockIdx.x;
    long long base = (long long)row * D_MODEL;
    int tid = threadIdx.x, lane = tid & 63, wave = tid >> 6;
    __shared__ float red[NCH][4];
    float hv[3];
    #pragma unroll
    for (int k = 0; k < 3; k++) hv[k] = h[base + tid + k * 256];
    float dot[NCH];
    #pragma unroll
    for (int i = 0; i < NCH; i++) {
        float d = 0.f;
        #pragma unroll
        for (int k = 0; k < 3; k++) d += hv[k] * gw[i * D_MODEL + tid + k * 256];
        dot[i] = wred_sum(d);
    }
    if (lane == 0)
        #pragma unroll
        for (int i = 0; i < NCH; i++) red[i][wave] = dot[i];
    __syncthreads();
    float coef[NCH];
    #pragma unroll
    for (int i = 0; i < NCH; i++) {
        float t = red[i][0] + red[i][1] + red[i][2] + red[i][3];
        float gate = 1.f / (1.f + __expf(-(t + gb[i])));
        coef[i] = log1pf(expf(sp[i])) * chamber_mask(i) * gate;
    }
    #pragma unroll
    for (int i = 0; i < NCH; i++) {
        const u16* Er = E + ((long long)i * ROWS + row) * D_MODEL;
        u16* dr = db + (long long)row * (NCH * D_MODEL) + i * D_MODEL;
        #pragma unroll
        for (int k = 0; k < 3; k++) {
            int c = tid + k * 256;
            dr[c] = f2bf(coef[i] * (bf2f(Er[c]) - hv[k]));
        }
    }
}

// ---------------------------------------------------------------------------
// seq delta: hh_new = hh + coef*(E - hh); writes hhf (f32) and hb (bf16)
// ---------------------------------------------------------------------------
__global__ __launch_bounds__(256)
void delta_seq_kernel(const u16* __restrict__ E, float* __restrict__ hhf,
                      u16* __restrict__ hb,
                      const float* __restrict__ gw, const float* __restrict__ gb,
                      const float* __restrict__ sp, int ci)
{
    int row = blockIdx.x;
    long long base = (long long)row * D_MODEL;
    int tid = threadIdx.x, lane = tid & 63, wave = tid >> 6;
    __shared__ float red[4];
    float hv[3]; float dot = 0.f;
    #pragma unroll
    for (int k = 0; k < 3; k++) {
        int c = tid + k * 256;
        hv[k] = hhf[base + c];
        dot += hv[k] * gw[ci * D_MODEL + c];
    }
    dot = wred_sum(dot);
    if (lane == 0) red[wave] = dot;
    __syncthreads();
    dot = red[0] + red[1] + red[2] + red[3];
    float gate = 1.f / (1.f + __expf(-(dot + gb[ci])));
    float coef = log1pf(expf(sp[ci])) * chamber_mask(ci) * gate;
    #pragma unroll
    for (int k = 0; k < 3; k++) {
        int c = tid + k * 256;
        float nh = hv[k] + coef * (bf2f(E[base + c]) - hv[k]);
        hhf[base + c] = nh;
        hb[base + c] = f2bf(nh);
    }
}

// ---------------------------------------------------------------------------
// weight transpose+cast into Wall with z-stride (interleave Wq/Wk per chamber)
// ---------------------------------------------------------------------------
__global__ __launch_bounds__(256)
void transw_kernel(const float* __restrict__ W, u16* __restrict__ WT, long long zstride)
{
    __shared__ u16 tile[32][33];
    int z = blockIdx.z;
    int c0 = blockIdx.x * 32, r0 = blockIdx.y * 32;
    int tx = threadIdx.x & 31, ty = threadIdx.x >> 5;
    const float* src = W + (long long)z * D_MODEL * D_MODEL;
    u16* dst = WT + (long long)z * zstride;
    #pragma unroll
    for (int i = 0; i < 32; i += 8)
        tile[ty + i][tx] = f2bf(src[(long long)(r0 + ty + i) * D_MODEL + c0 + tx]);
    __syncthreads();
    #pragma unroll
    for (int i = 0; i < 32; i += 8)
        dst[(long long)(c0 + ty + i) * D_MODEL + r0 + tx] = tile[tx][ty + i];
}

__global__ __launch_bounds__(256)
void cast_kernel(const float* __restrict__ in, u16* __restrict__ outp, int n)
{
    int i = blockIdx.x * 256 + threadIdx.x;
    if (i < n) outp[i] = f2bf(in[i]);
}

// ---------------------------------------------------------------------------
// final: e = (1-mg)*(hhf-h) + mg*par; out = x + rg*(LN(e)*g+b)
// ---------------------------------------------------------------------------
__global__ __launch_bounds__(256)
void final_kernel(const float* __restrict__ x, const float* __restrict__ h,
                  const float* __restrict__ hhf, const float* __restrict__ par,
                  const float* __restrict__ mode_logit, const float* __restrict__ residual_gate,
                  const float* __restrict__ g, const float* __restrict__ b,
                  float* __restrict__ out)
{
    int row = blockIdx.x;
    long long base = (long long)row * D_MODEL;
    int tid = threadIdx.x, lane = tid & 63, wave = tid >> 6;
    __shared__ float red[4];
    float mg = 1.f / (1.f + __expf(-mode_logit[0]));
    float rg = residual_gate[0];
    float e[3]; float s = 0.f;
    #pragma unroll
    for (int k = 0; k < 3; k++) {
        int c = tid + k * 256;
        float v = (1.f - mg) * (hhf[base + c] - h[base + c]) + mg * par[base + c];
        e[k] = v; s += v;
    }
    s = wred_sum(s);
    if (lane == 0) red[wave] = s;
    __syncthreads();
    float mean = (red[0] + red[1] + red[2] + red[3]) * (1.f / D_MODEL);
    __syncthreads();
    float sq = 0.f;
    #pragma unroll
    for (int k = 0; k < 3; k++) { float d = e[k] - mean; sq += d * d; }
    sq = wred_sum(sq);
    if (lane == 0) red[wave] = sq;
    __syncthreads();
    float var = (red[0] + red[1] + red[2] + red[3]) * (1.f / D_MODEL);
    float rstd = rsqrtf(var + 1e-5f);
    #pragma unroll
    for (int k = 0; k < 3; k++) {
        int c = tid + k * 256;
        out[base + c] = x[base + c] + rg * ((e[k] - mean) * rstd * g[c] + b[c]);
    }
}

// ---------------------------------------------------------------------------
extern "C" void kernel_launch(void* const* d_in, const int* in_sizes, int n_in,
                              void* d_out, int out_size, void* d_ws, size_t ws_size,
                              hipStream_t stream)
{
    (void)in_sizes; (void)n_in; (void)out_size; (void)ws_size;
    const float* x             = (const float*)d_in[0];
    const float* Wq            = (const float*)d_in[1];
    const float* Wk            = (const float*)d_in[2];
    const float* gate_w        = (const float*)d_in[3];
    const float* gate_b        = (const float*)d_in[4];
    const float* scale_p       = (const float*)d_in[5];
    const float* merge_W       = (const float*)d_in[6];
    const float* mode_logit    = (const float*)d_in[7];
    const float* residual_gate = (const float*)d_in[8];
    const float* ln_pre_g      = (const float*)d_in[9];
    const float* ln_pre_b      = (const float*)d_in[10];
    const float* ln_post_g     = (const float*)d_in[11];
    const float* ln_post_b     = (const float*)d_in[12];
    float* out = (float*)d_out;

    const long long DD  = (long long)D_MODEL * D_MODEL;   // 589824
    const long long TD  = (long long)T_SEQ * D_MODEL;     // 786432
    const long long TTs = (long long)T_SEQ * T_SEQ;       // 1048576
    const long long RDe = (long long)ROWS * D_MODEL;      // 3145728
    const int KM = NCH * D_MODEL;                         // 5376

    size_t off = 0;
    char* wsb = (char*)d_ws;
    auto alloc = [&](size_t bytes) -> void* {
        void* p = wsb + off; off += (bytes + 255) & ~(size_t)255; return p;
    };
    u16*  Wall = (u16*)alloc((size_t)NCH * 2 * DD * 2);        // [i][q/k][768][768]
    u16*  mgb  = (u16*)alloc((size_t)D_MODEL * KM * 2);        // merge_W bf16
    float* h   = (float*)alloc(RDe * 4);
    float* hhf = (float*)alloc(RDe * 4);                       // h + seq (running)
    float* par = (float*)alloc(RDe * 4);
    u16*  hb   = (u16*)alloc(RDe * 2);
    u16*  ht   = (u16*)alloc(RDe * 2);
    u16*  S    = (u16*)alloc((size_t)(NCH * BATCH) * TTs * 2); // f16 scores -> bf16 P; db aliases
    u16*  qk   = (u16*)alloc((size_t)(NCH * 2) * RDe * 2);     // par q/k; E_all aliases
    u16*  qkb  = (u16*)alloc((size_t)ROWS * 1536 * 2);         // seq q|k
    u16*  Eseq = (u16*)alloc(RDe * 2);
    u16*  Eall = qk;                                           // alias (qk dead after scores)
    u16*  db   = S;                                            // alias (P dead after PV)

    const float sc = 1.0f / sqrtf((float)D_MODEL);

    hipMemsetAsync(par, 0, RDe * 4, stream);                   // split-K atomic target

    ln_pre_kernel<<<ROWS, 256, 0, stream>>>(x, ln_pre_g, ln_pre_b, h, hhf, hb);
    transw_kernel<<<dim3(24, 24, NCH), 256, 0, stream>>>(Wq, Wall, 2 * DD);
    transw_kernel<<<dim3(24, 24, NCH), 256, 0, stream>>>(Wk, Wall + DD, 2 * DD);
    cast_kernel<<<((int)(D_MODEL * KM) + 255) / 256, 256, 0, stream>>>(merge_W, mgb, D_MODEL * KM);
    transpose_kernel<<<dim3(24, 32, BATCH), 256, 0, stream>>>(hb, ht);

    // ======================= par branch (batched over chambers) ==============
    // proj: qk[z] = hb @ Wall[z]^T, z = 0..13  (z = 2i+w)
    gemm_nt_kernel<<<dim3(6, 32, 2 * NCH), 256, 0, stream>>>(
        hb, Wall, qk, D_MODEL, D_MODEL, D_MODEL, D_MODEL,
        0, 0, DD, 0, RDe, 0, 2 * NCH, 1.f, 1, 0, 0, 0, 0);
    // scores: S[i*4+b] = Q_i[b] K_i[b]^T / sqrt(D), causal, f16
    gemm_nt_kernel<<<dim3(8, 8, BATCH * NCH), 256, 0, stream>>>(
        qk, qk + RDe, S, D_MODEL, D_MODEL, D_MODEL, T_SEQ,
        TD, 2 * RDe, TD, 2 * RDe, TTs, 4 * TTs, BATCH, sc, 3, 1, 0, 0, 0);
    softmax_kernel<<<dim3(T_SEQ, BATCH * NCH), 256, 0, stream>>>(S);
    // PV: E[z] = P[z] @ ht[b]^T (bf16 out), causal K-limit
    gemm_nt_kernel<<<dim3(6, 8, BATCH * NCH), 256, 0, stream>>>(
        S, ht, Eall, T_SEQ, T_SEQ, T_SEQ, D_MODEL,
        TTs, 4 * TTs, TD, 0, TD, 4 * TD, BATCH, 1.f, 1, 0, 1, 0, 0);
    delta_par_kernel<<<ROWS, 256, 0, stream>>>(Eall, h, db, gate_w, gate_b, scale_p);
    // merge: par += db @ mgb^T, split-K x4 with atomic accumulate
    gemm_nt_kernel<<<dim3(6, 32, 4), 256, 0, stream>>>(
        db, mgb, par, KM, KM, KM, D_MODEL,
        0, 0, 0, 0, 0, 0, 4, 1.f, 4, 0, 0, KM / 4, KM / 4);

    // ======================= seq branch (serial chain) =======================
    for (int i = 0; i < NCH; i++) {
        // qkb[:, w*768:] = hb @ Wall[2i+w]^T
        gemm_nt_kernel<<<dim3(6, 32, 2), 256, 0, stream>>>(
            hb, Wall + (long long)i * 2 * DD, qkb, D_MODEL, D_MODEL, D_MODEL, 1536,
            0, 0, DD, 0, 768, 0, 2, 1.f, 1, 0, 0, 0, 0);
        gemm_nt_kernel<<<dim3(8, 8, BATCH), 256, 0, stream>>>(
            qkb, qkb + 768, S, D_MODEL, 1536, 1536, T_SEQ,
            (long long)T_SEQ * 1536, 0, (long long)T_SEQ * 1536, 0, TTs, 0, BATCH,
            sc, 3, 1, 0, 0, 0);
        softmax_kernel<<<dim3(T_SEQ, BATCH), 256, 0, stream>>>(S);
        gemm_nt_kernel<<<dim3(6, 8, BATCH), 256, 0, stream>>>(
            S, ht, Eseq, T_SEQ, T_SEQ, T_SEQ, D_MODEL,
            TTs, 0, TD, 0, TD, 0, BATCH, 1.f, 1, 0, 1, 0, 0);
        delta_seq_kernel<<<ROWS, 256, 0, stream>>>(Eseq, hhf, hb, gate_w, gate_b, scale_p, i);
        if (i < NCH - 1)
            transpose_kernel<<<dim3(24, 32, BATCH), 256, 0, stream>>>(hb, ht);
    }

    final_kernel<<<ROWS, 256, 0, stream>>>(x, h, hhf, par, mode_logit, residual_gate,
                                           ln_post_g, ln_post_b, out);
}